// Round 8
// baseline (133.803 us; speedup 1.0000x reference)
//
#include <hip/hip_runtime.h>
#include <hip/hip_bf16.h>

#define B_ 1024
#define IN_ 512
#define OUT_ 512
#define BTILE 32
#define OTILE 32
#define ITILE 8
#define KSPLIT 8
#define KCHUNK (IN_ / KSPLIT)          // 64 i's per block
#define NCHUNKS (KCHUNK / ITILE)       // 8 staging chunks
#define THREADS 128
#define P4ROW 132   // floats per i-row of p4 (32 o * 4 + 4 pad; 8-lane write/read phases clean)
#define PLROW 33    // floats per i-row of lw (32 + 1 pad)
#define XSTRIDE 36  // x row: 32 b + 4 pad (b128 reads 16B-aligned)
#define SASTRIDE 8  // sA/wB row = 8 bf16 = 16 B (K=8 per chunk, b128 frag reads)

typedef float v2f   __attribute__((ext_vector_type(2)));
typedef float f32x4 __attribute__((ext_vector_type(4)));
typedef short s16x8 __attribute__((ext_vector_type(8)));   // 8 bf16 = 4 VGPRs
#define PKFMA(a, b, c) __builtin_elementwise_fma((v2f)(a), (v2f)(b), (v2f)(c))

__device__ __forceinline__ unsigned short f2bf(float f) {
    union { float f; unsigned int u; } v; v.f = f;
    unsigned int b = v.u + 0x7FFFu + ((v.u >> 16) & 1u);   // RNE
    return (unsigned short)(b >> 16);
}
__device__ __forceinline__ float fast_exp2(float x) {
#if __has_builtin(__builtin_amdgcn_exp2f)
    return __builtin_amdgcn_exp2f(x);
#else
    return __exp2f(x);
#endif
}
__device__ __forceinline__ float fast_log2(float x) {
#if __has_builtin(__builtin_amdgcn_logf)
    return __builtin_amdgcn_logf(x);
#else
    return __log2f(x);
#endif
}
__device__ __forceinline__ float fast_cos_rev(float x) {  // cos(2*pi*x), revolutions
#if __has_builtin(__builtin_amdgcn_cosf)
    return __builtin_amdgcn_cosf(x);   // ~12 busy-cyc/wave64 (R6/R14 back-solves);
                                       // poly replacement measured WORSE (R15)
#else
    return __cosf(x * 6.2831853071795864f);
#endif
}
__device__ __forceinline__ float fast_rcp(float x) {
#if __has_builtin(__builtin_amdgcn_rcpf)
    return __builtin_amdgcn_rcpf(x);
#else
    return 1.0f / x;
#endif
}

__global__ __launch_bounds__(THREADS, 8) void chirplet_kernel(
    const float* __restrict__ x,
    const float* __restrict__ W,
    const float* __restrict__ Wc,
    const float* __restrict__ S,
    const float* __restrict__ T,
    const float* __restrict__ F,
    const float* __restrict__ bias,
    float* __restrict__ out)
{
    // R23: maximize intra-CU de-phasing. Evidence across R14-R22: busy is pinned
    // at the serialized 56-cyc/unit trans floor (~49-52us); idle (16-43us) tracks
    // ONE variable -- independent barrier domains per CU covering each other's
    // stage stalls (2-round configs idle ~16.5; 1-round ~22+). Here: 128-thread
    // blocks -> 16 co-resident blocks/CU (vs 8), 16 barrier domains, each barrier
    // syncs only 2 waves. Grid 16x32x8 = 4096 x 128thr = 8192 waves = exactly
    // full residency. Per-thread shape = R14's proven 2o x 4b; KSPLIT 8 keeps
    // WRITE 16 MB (R22); per-chunk K=8 micro-MFMA = R18's verified pattern;
    // param staging via float2-pair loads (same load count/thread as R14).
    __shared__ __align__(16) float p4_lds[ITILE * P4ROW];    // 4.1 KB {a,b',c2,d2} [i][o]
    __shared__ __align__(16) float plw_lds[ITILE * PLROW];   // 1.0 KB log2|Wc| [i][o]
    __shared__ __align__(16) float x_lds[ITILE * XSTRIDE];   // 1.1 KB x fp32 [i][b]
    __shared__ __align__(16) unsigned short sA_lds[BTILE * SASTRIDE]; // 0.5 KB silu bf16 [b][k8]
    __shared__ __align__(16) unsigned short wB_lds[OTILE * SASTRIDE]; // 0.5 KB W bf16 [o][k8]
    // total ~7.3 KB -> 16 blocks/CU = 117 KB (wave-cap bound at 32 waves/CU)

    const int tid  = threadIdx.x;
    const int wave = tid >> 6;          // 0..1
    const int lane = tid & 63;
    const int o0 = blockIdx.x * OTILE;
    const int b0 = blockIdx.y * BTILE;
    const int k0 = blockIdx.z * KCHUNK;

    const int oc = lane & 15;           // o col (MFMA C col); o = o0 + oc + o2*16
    const int lq = lane >> 4;           // quad; b = b0 + wave*16 + lq*4 + reg (MFMA C row)
    const int xb = wave * 16 + lq * 4;  // x read base (b)

    const int xr = tid >> 2;            // x stage: b row 0..31
    const int xq = tid & 3;             // i pair: i = xq*2 + j

    const int po = tid & 31;            // param o 0..31
    const int ph = tid >> 5;            // param i-pair 0..3 -> i = ph*2 + j

    const float LOG2E = 1.4426950408889634f;
    const float GK    = 0.8493218002880191f;   // sqrt(0.5*log2(e))

    v2f acc2[2][2] = {{{0.f,0.f},{0.f,0.f}},{{0.f,0.f},{0.f,0.f}}};  // [o2][p]
    f32x4 accg[2] = {{0.f,0.f,0.f,0.f},{0.f,0.f,0.f,0.f}};           // MFMA [o2]

    for (int c = 0; c < NCHUNKS; ++c) {
        const int ib = k0 + c * ITILE;

        // ---- stage x tile: float2/thread -> x fp32 [i][b] + silu bf16 [b][k8]
        {
            const float2 v = *(const float2*)(x + (size_t)(b0 + xr) * IN_ + ib + xq * 2);
            const float xf[2] = { v.x, v.y };
            unsigned int packed = 0;
            #pragma unroll
            for (int j = 0; j < 2; ++j) {
                const int col = xq * 2 + j;
                const float xv  = xf[j];
                const float sig = fast_rcp(1.0f + fast_exp2(-xv * LOG2E));
                x_lds[col * XSTRIDE + xr] = xv;
                packed |= (unsigned int)f2bf(xv * sig) << (16 * j);
            }
            *(unsigned int*)&sA_lds[xr * SASTRIDE + xq * 2] = packed;
        }

        // ---- stage params: 32 o x 8 i; float2-pair loads (i slots ph*2, ph*2+1)
        {
            const size_t go = (size_t)(o0 + po) * IN_ + ib + ph * 2;
            const float2 s2  = *(const float2*)(S + go);
            const float2 t2  = *(const float2*)(T + go);
            const float2 f2  = *(const float2*)(F + go);
            const float2 wc2 = *(const float2*)(Wc + go);
            const float2 w2  = *(const float2*)(W + go);
            const float sA[2]  = { s2.x, s2.y };
            const float tA[2]  = { t2.x, t2.y };
            const float fA[2]  = { f2.x, f2.y };
            const float wcA[2] = { wc2.x, wc2.y };
            unsigned int wpk = 0;
            #pragma unroll
            for (int j = 0; j < 2; ++j) {
                const int slot = ph * 2 + j;
                const float rs = fast_rcp(sA[j]);
                const float a  = fA[j] * rs;                   // revolutions per x
                float4 p0;
                p0.x = a;
                p0.y = -a * tA[j] + (wcA[j] < 0.0f ? 0.5f : 0.0f);  // phase + sign(Wc)
                p0.z = rs * GK;
                p0.w = -tA[j] * rs * GK;
                *(float4*)&p4_lds[slot * P4ROW + po * 4] = p0;
                plw_lds[slot * PLROW + po] = fast_log2(fabsf(wcA[j]));
                wpk |= (unsigned int)f2bf(j == 0 ? w2.x : w2.y) << (16 * j);
            }
            *(unsigned int*)&wB_lds[po * SASTRIDE + ph * 2] = wpk;
        }
        __syncthreads();

        // ---- micro-GEMM on matrix pipe: K=8 valid (lanes 0-15), accumulate in C
        {
            s16x8 af = {0,0,0,0,0,0,0,0}, bf0 = af, bf1 = af;
            if (lane < 16) {
                af  = *(const s16x8*)&sA_lds[(wave * 16 + (lane & 15)) * SASTRIDE];
                bf0 = *(const s16x8*)&wB_lds[(lane & 15) * SASTRIDE];
                bf1 = *(const s16x8*)&wB_lds[((lane & 15) + 16) * SASTRIDE];
            }
            accg[0] = __builtin_amdgcn_mfma_f32_16x16x32_bf16(af, bf0, accg[0], 0, 0, 0);
            accg[1] = __builtin_amdgcn_mfma_f32_16x16x32_bf16(af, bf1, accg[1], 0, 0, 0);
        }

        // ---- compute: chirplet, 8 i x 2 o x 2 b-pair units per thread (R14 shape)
        #pragma unroll 4
        for (int i = 0; i < ITILE; ++i) {
            const float4 abcd[2] = {
                *(const float4*)&p4_lds[i * P4ROW + oc * 4],
                *(const float4*)&p4_lds[i * P4ROW + (oc + 16) * 4] };
            const float lw[2] = {
                plw_lds[i * PLROW + oc],
                plw_lds[i * PLROW + oc + 16] };
            const f32x4 xk4 = *(const f32x4*)&x_lds[i * XSTRIDE + xb];
            const v2f xk2[2] = {
                __builtin_shufflevector(xk4, xk4, 0, 1),
                __builtin_shufflevector(xk4, xk4, 2, 3) };
            #pragma unroll
            for (int o = 0; o < 2; ++o) {
                const v2f aa = { abcd[o].x, abcd[o].x };
                const v2f bb = { abcd[o].y, abcd[o].y };
                const v2f cc = { abcd[o].z, abcd[o].z };
                const v2f dd = { abcd[o].w, abcd[o].w };
                const v2f lwv = { lw[o], lw[o] };
                #pragma unroll
                for (int p = 0; p < 2; ++p) {
                    v2f rev = PKFMA(aa, xk2[p], bb);       // phase (revs)
                    v2f u   = PKFMA(cc, xk2[p], dd);       // GK*(x-t)/s
                    v2f arg = PKFMA(-u, u, lwv);           // lw - u^2
                    v2f co, e;
                    co.x = fast_cos_rev(rev.x);
                    co.y = fast_cos_rev(rev.y);
                    e.x  = fast_exp2(arg.x);
                    e.y  = fast_exp2(arg.y);
                    acc2[o][p] = PKFMA(co, e, acc2[o][p]); // chirplet
                }
            }
        }
        __syncthreads();
    }

    // ---- epilogue: chirplet + MFMA (same C layout) + bias; 8 atomics/thread
    const float badd[2] = { (blockIdx.z == 0) ? bias[o0 + oc] : 0.0f,
                            (blockIdx.z == 0) ? bias[o0 + oc + 16] : 0.0f };
    #pragma unroll
    for (int o = 0; o < 2; ++o) {
        #pragma unroll
        for (int p = 0; p < 2; ++p) {
            #pragma unroll
            for (int j = 0; j < 2; ++j) {
                const int reg = p * 2 + j;
                const int b = b0 + wave * 16 + lq * 4 + reg;
                float* dst = &out[(size_t)b * OUT_ + o0 + oc + o * 16];
                const float val = (j == 0 ? acc2[o][p].x : acc2[o][p].y)
                                + accg[o][reg] + badd[o];
#if defined(__HIP_DEVICE_COMPILE__)
                unsafeAtomicAdd(dst, val);   // HW global_atomic_add_f32
#else
                atomicAdd(dst, val);
#endif
            }
        }
    }
}

extern "C" void kernel_launch(void* const* d_in, const int* in_sizes, int n_in,
                              void* d_out, int out_size, void* d_ws, size_t ws_size,
                              hipStream_t stream) {
    const float* x    = (const float*)d_in[0];
    const float* W    = (const float*)d_in[1];
    const float* Wc   = (const float*)d_in[2];
    const float* S    = (const float*)d_in[3];
    const float* T    = (const float*)d_in[4];
    const float* F    = (const float*)d_in[5];
    const float* bias = (const float*)d_in[6];
    float* out = (float*)d_out;

    // d_out is poisoned before every launch; atomics need zeroed destination
    hipMemsetAsync(out, 0, (size_t)out_size * sizeof(float), stream);

    dim3 grid(OUT_ / OTILE, B_ / BTILE, KSPLIT);   // 16 x 32 x 8 = 4096 blocks x 128thr
    chirplet_kernel<<<grid, THREADS, 0, stream>>>(x, W, Wc, S, T, F, bias, out);
}